// Round 4
// baseline (605.074 us; speedup 1.0000x reference)
//
#include <hip/hip_runtime.h>

#define CIN  32
#define COUT 32
#define KK   27

// ---------------- Kernel 1: transpose x [Cin,N] -> xT [N,Cin] ----------------
__global__ __launch_bounds__(256) void transpose_k(const float* __restrict__ in,
                                                   float* __restrict__ xT, int N) {
    __shared__ float tile[32][33];
    int n0 = blockIdx.x * 32;
    int tx = threadIdx.x & 31;
    int ty = threadIdx.x >> 5;  // 0..7
#pragma unroll
    for (int c = ty; c < 32; c += 8) {
        int n = n0 + tx;
        tile[c][tx] = (n < N) ? in[(long)c * N + n] : 0.f;
    }
    __syncthreads();
#pragma unroll
    for (int nn = ty; nn < 32; nn += 8) {
        int n = n0 + nn;
        if (n < N) xT[(long)n * 32 + tx] = tile[tx][nn];
    }
}

// ---------------- Kernel 2: conv + per-wave BN partials ----------------
// 256 threads = 64 nodes x 4 tap-groups (group == wave, so the tap range is
// wave-uniform and the weights compile to SGPR s_loads). 4x the waves of the
// 1-thread-per-node version with identical gather traffic -> latency hiding
// by TLP. Partial accs combined via padded LDS, y written coalesced.
__global__ __launch_bounds__(256, 4) void conv_k(const float* __restrict__ xT,
                                                 const int* __restrict__ neigh,
                                                 const float* __restrict__ weight,
                                                 float* __restrict__ y,        // d_out, [COUT][N]
                                                 float* __restrict__ partial,  // [64][nrows]
                                                 int N, int nrows) {
    __shared__ float lacc[4][64][33];   // +1 pad: stride 33 -> 2 lanes/bank (free)

    const int tid   = threadIdx.x;
    const int ln    = tid & 63;          // node within block
    const int g     = tid >> 6;          // tap group == wave id
    const int node  = blockIdx.x * 64 + ln;
    const bool valid = (node < N);
    const long nb   = (long)(valid ? node : 0) * KK;

    const int kbeg = g * 7;                      // 0,7,14,21
    const int kend = (g == 3) ? KK : (kbeg + 7); // counts 7,7,7,6 (wave-uniform)

    float acc[COUT];
#pragma unroll
    for (int d = 0; d < COUT; ++d) acc[d] = 0.f;

    int m  = neigh[nb + kbeg];
    int m2 = neigh[nb + kbeg + 1];

    // prologue: load first tap's row (contiguous 128 B)
    const float4* xr = (const float4*)(xT + (long)m * CIN);
    float4 x0 = xr[0], x1 = xr[1], x2 = xr[2], x3 = xr[3];
    float4 x4 = xr[4], x5 = xr[5], x6 = xr[6], x7 = xr[7];

#define DOT4(xq, cb) do {                                      \
        const float* W0 = wk + (cb + 0) * COUT;                \
        const float* W1 = wk + (cb + 1) * COUT;                \
        const float* W2 = wk + (cb + 2) * COUT;                \
        const float* W3 = wk + (cb + 3) * COUT;                \
        _Pragma("unroll")                                      \
        for (int d = 0; d < COUT; ++d) {                       \
            float t = acc[d];                                  \
            t = fmaf((xq).x, W0[d], t);                        \
            t = fmaf((xq).y, W1[d], t);                        \
            t = fmaf((xq).z, W2[d], t);                        \
            t = fmaf((xq).w, W3[d], t);                        \
            acc[d] = t;                                        \
        }                                                      \
    } while (0)

#pragma unroll 1
    for (int k = kbeg; k < kend; ++k) {
        // batched prefetch of next tap's row (independent of the FMA block)
        const float4* xp = (const float4*)(xT + (long)m2 * CIN);
        float4 p0 = xp[0], p1 = xp[1], p2 = xp[2], p3 = xp[3];
        float4 p4 = xp[4], p5 = xp[5], p6 = xp[6], p7 = xp[7];
        m2 = neigh[nb + ((k + 2 < kend) ? (k + 2) : (kend - 1))];

        __builtin_amdgcn_sched_barrier(0);  // loads stay above the FMA block

        const float* wk = weight + k * (CIN * COUT);
        DOT4(x0, 0);  DOT4(x1, 4);  DOT4(x2, 8);  DOT4(x3, 12);
        DOT4(x4, 16); DOT4(x5, 20); DOT4(x6, 24); DOT4(x7, 28);

        __builtin_amdgcn_sched_barrier(0);  // rotation waitcnt stays below

        x0 = p0; x1 = p1; x2 = p2; x3 = p3;
        x4 = p4; x5 = p5; x6 = p6; x7 = p7;
    }
#undef DOT4

    // combine the 4 tap-group partials through LDS
#pragma unroll
    for (int d = 0; d < COUT; ++d) lacc[g][ln][d] = acc[d];
    __syncthreads();

    // each thread finalizes channels {g, g+4, ..., g+28} of node ln:
    // y writes are 64 consecutive nodes per wave (coalesced), BN partials via
    // 64-lane butterfly (lanes of a wave share the channel).
#pragma unroll
    for (int i = 0; i < 8; ++i) {
        const int ch = g + i * 4;
        float v = lacc[0][ln][ch] + lacc[1][ln][ch] + lacc[2][ln][ch] + lacc[3][ln][ch];
        if (valid) y[(long)ch * N + node] = v;
        else       v = 0.f;
        float s = v;
        float q = v * v;
#pragma unroll
        for (int off = 1; off < 64; off <<= 1) {
            s += __shfl_xor(s, off, 64);
            q += __shfl_xor(q, off, 64);
        }
        if (ln == 0) {
            partial[(long)ch * nrows + blockIdx.x]        = s;
            partial[(long)(ch + 32) * nrows + blockIdx.x] = q;
        }
    }
}

// ---------------- Kernel 3: column reduce partial[64][nrows] -> tot[64] ----
__global__ __launch_bounds__(256) void stats1_k(const float* __restrict__ partial,
                                                int nrows, float* __restrict__ tot) {
    __shared__ float red[256];
    const int col = blockIdx.x;  // 0..63
    const float* row = partial + (long)col * nrows;
    float s = 0.f;
    for (int r = threadIdx.x; r < nrows; r += 256) s += row[r];
    red[threadIdx.x] = s;
    __syncthreads();
    for (int w = 128; w >= 64; w >>= 1) {
        if (threadIdx.x < w) red[threadIdx.x] += red[threadIdx.x + w];
        __syncthreads();
    }
    if (threadIdx.x < 64) {
        float v = red[threadIdx.x];
#pragma unroll
        for (int off = 1; off < 64; off <<= 1) v += __shfl_xor(v, off, 64);
        if (threadIdx.x == 0) tot[col] = v;
    }
}

// ---------------- Kernel 4: normalize y in place (stats finalize fused) ----
__global__ __launch_bounds__(256) void norm_k(float* __restrict__ y,
                                              const float* __restrict__ tot,
                                              const float* __restrict__ gamma,
                                              const float* __restrict__ beta, int N) {
    const int d = blockIdx.y;
    const float mean = tot[d] / (float)N;
    const float var  = tot[d + 32] / (float)N - mean * mean;
    const float sc   = gamma[d] * rsqrtf(var + 1e-3f);
    const float sh   = beta[d] - mean * sc;

    int i = blockIdx.x * blockDim.x + threadIdx.x;
    int base = i * 4;
    if (base + 3 < N) {
        float4* p = (float4*)(y + (long)d * N + base);
        float4 v = *p;
        v.x = fmaf(v.x, sc, sh);
        v.y = fmaf(v.y, sc, sh);
        v.z = fmaf(v.z, sc, sh);
        v.w = fmaf(v.w, sc, sh);
        *p = v;
    } else if (base < N) {
        for (int t = base; t < N; ++t) y[(long)d * N + t] = fmaf(y[(long)d * N + t], sc, sh);
    }
}

// ---------------- launcher ----------------
extern "C" void kernel_launch(void* const* d_in, const int* in_sizes, int n_in,
                              void* d_out, int out_size, void* d_ws, size_t ws_size,
                              hipStream_t stream) {
    const float* data_in = (const float*)d_in[0];
    const int*   neigh   = (const int*)d_in[1];
    const float* weight  = (const float*)d_in[2];
    const float* gamma   = (const float*)d_in[3];
    const float* beta    = (const float*)d_in[4];
    float* out = (float*)d_out;

    const int N = in_sizes[1] / KK;

    float* xT = (float*)d_ws;                        // N*32 floats
    const int nblk  = (N + 63) / 64;                 // conv blocks (64 nodes each)
    const int nrows = nblk;
    float* partial = xT + (size_t)N * CIN;           // 64*nrows floats
    float* tot     = partial + (size_t)64 * nrows;   // 64 floats

    transpose_k<<<(N + 31) / 32, 256, 0, stream>>>(data_in, xT, N);
    conv_k<<<nblk, 256, 0, stream>>>(xT, neigh, weight, out, partial, N, nrows);
    stats1_k<<<64, 256, 0, stream>>>(partial, nrows, tot);
    dim3 ngrid(((N + 3) / 4 + 255) / 256, COUT);
    norm_k<<<ngrid, 256, 0, stream>>>(out, tot, gamma, beta, N);
}

// Round 5
// 547.862 us; speedup vs baseline: 1.1044x; 1.1044x over previous
//
#include <hip/hip_runtime.h>

#define CIN  32
#define COUT 32
#define KK   27

// ---------------- Kernel 1: transpose x [Cin,N] -> xT [N,Cin] ----------------
__global__ __launch_bounds__(256) void transpose_k(const float* __restrict__ in,
                                                   float* __restrict__ xT, int N) {
    __shared__ float tile[32][33];
    int n0 = blockIdx.x * 32;
    int tx = threadIdx.x & 31;
    int ty = threadIdx.x >> 5;  // 0..7
#pragma unroll
    for (int c = ty; c < 32; c += 8) {
        int n = n0 + tx;
        tile[c][tx] = (n < N) ? in[(long)c * N + n] : 0.f;
    }
    __syncthreads();
#pragma unroll
    for (int nn = ty; nn < 32; nn += 8) {
        int n = n0 + nn;
        if (n < N) xT[(long)n * 32 + tx] = tile[tx][nn];
    }
}

// ---------------- Kernel 2: conv + per-wave BN partials ----------------
// 256 threads = 64 nodes x (2 tap-halves x 2 channel-halves). Wave id g
// encodes (tap-half tg, channel-half h) -> both wave-uniform -> weights are
// SGPR s_loads. Per thread: acc[16] + one x-row[32] ~= 55 VGPRs -> fits the
// 64-VGPR / 8-waves-per-EU bucket WITHOUT SPILL (round-4 spilled at acc[32]).
__global__ __launch_bounds__(256, 8) void conv_k(const float* __restrict__ xT,
                                                 const int* __restrict__ neigh,
                                                 const float* __restrict__ weight,
                                                 float* __restrict__ y,        // d_out, [COUT][N]
                                                 float* __restrict__ partial,  // [64][nrows]
                                                 int N, int nrows) {
    __shared__ float lacc[2][2][64][17];   // [tg][h][node][ch] pad->conflict-free

    const int tid   = threadIdx.x;
    const int ln    = tid & 63;          // node within block
    const int g     = tid >> 6;          // wave id 0..3
    const int tg    = g >> 1;            // tap half
    const int h     = g & 1;             // channel half
    const int node  = blockIdx.x * 64 + ln;
    const bool valid = (node < N);
    const long nb   = (long)(valid ? node : 0) * KK;

    const int kbeg = tg * 14;            // 0 / 14
    const int kend = tg ? KK : 14;       // 14 / 13 taps
    const int ch0  = h * 16;

    float acc[16];
#pragma unroll
    for (int d = 0; d < 16; ++d) acc[d] = 0.f;

    int m = neigh[nb + kbeg];

#define DOT4H(xq, cb) do {                                     \
        const float* W0 = wk + (cb + 0) * COUT;                \
        const float* W1 = wk + (cb + 1) * COUT;                \
        const float* W2 = wk + (cb + 2) * COUT;                \
        const float* W3 = wk + (cb + 3) * COUT;                \
        _Pragma("unroll")                                      \
        for (int d = 0; d < 16; ++d) {                         \
            float t = acc[d];                                  \
            t = fmaf((xq).x, W0[d], t);                        \
            t = fmaf((xq).y, W1[d], t);                        \
            t = fmaf((xq).z, W2[d], t);                        \
            t = fmaf((xq).w, W3[d], t);                        \
            acc[d] = t;                                        \
        }                                                      \
    } while (0)

#pragma unroll 1
    for (int k = kbeg; k < kend; ++k) {
        // gather this tap's full row (contiguous 128 B, batched dwordx4)
        const float4* xr = (const float4*)(xT + (long)m * CIN);
        float4 a0 = xr[0], a1 = xr[1], a2 = xr[2], a3 = xr[3];
        float4 a4 = xr[4], a5 = xr[5], a6 = xr[6], a7 = xr[7];
        // prefetch next neighbor index
        m = neigh[nb + ((k + 1 < kend) ? (k + 1) : (kend - 1))];

        const float* wk = weight + k * (CIN * COUT) + ch0;
        DOT4H(a0, 0);  DOT4H(a1, 4);  DOT4H(a2, 8);  DOT4H(a3, 12);
        DOT4H(a4, 16); DOT4H(a5, 20); DOT4H(a6, 24); DOT4H(a7, 28);
    }
#undef DOT4H

    // combine tap-half partials through LDS
#pragma unroll
    for (int d = 0; d < 16; ++d) lacc[tg][h][ln][d] = acc[d];
    __syncthreads();

    // each thread finalizes channels {g, g+4, ..., g+28} of node ln:
    // coalesced y writes + 64-lane butterfly for BN partials
#pragma unroll
    for (int i = 0; i < 8; ++i) {
        const int ch = g + i * 4;
        const int hh = ch >> 4;
        const int dd = ch & 15;
        float v = lacc[0][hh][ln][dd] + lacc[1][hh][ln][dd];
        if (valid) y[(long)ch * N + node] = v;
        else       v = 0.f;
        float s = v;
        float q = v * v;
#pragma unroll
        for (int off = 1; off < 64; off <<= 1) {
            s += __shfl_xor(s, off, 64);
            q += __shfl_xor(q, off, 64);
        }
        if (ln == 0) {
            partial[(long)ch * nrows + blockIdx.x]        = s;
            partial[(long)(ch + 32) * nrows + blockIdx.x] = q;
        }
    }
}

// ---------------- Kernel 3: column reduce partial[64][nrows] -> tot[64] ----
__global__ __launch_bounds__(256) void stats1_k(const float* __restrict__ partial,
                                                int nrows, float* __restrict__ tot) {
    __shared__ float red[256];
    const int col = blockIdx.x;  // 0..63
    const float* row = partial + (long)col * nrows;
    float s = 0.f;
    for (int r = threadIdx.x; r < nrows; r += 256) s += row[r];
    red[threadIdx.x] = s;
    __syncthreads();
    for (int w = 128; w >= 64; w >>= 1) {
        if (threadIdx.x < w) red[threadIdx.x] += red[threadIdx.x + w];
        __syncthreads();
    }
    if (threadIdx.x < 64) {
        float v = red[threadIdx.x];
#pragma unroll
        for (int off = 1; off < 64; off <<= 1) v += __shfl_xor(v, off, 64);
        if (threadIdx.x == 0) tot[col] = v;
    }
}

// ---------------- Kernel 4: normalize y in place (stats finalize fused) ----
__global__ __launch_bounds__(256) void norm_k(float* __restrict__ y,
                                              const float* __restrict__ tot,
                                              const float* __restrict__ gamma,
                                              const float* __restrict__ beta, int N) {
    const int d = blockIdx.y;
    const float mean = tot[d] / (float)N;
    const float var  = tot[d + 32] / (float)N - mean * mean;
    const float sc   = gamma[d] * rsqrtf(var + 1e-3f);
    const float sh   = beta[d] - mean * sc;

    int i = blockIdx.x * blockDim.x + threadIdx.x;
    int base = i * 4;
    if (base + 3 < N) {
        float4* p = (float4*)(y + (long)d * N + base);
        float4 v = *p;
        v.x = fmaf(v.x, sc, sh);
        v.y = fmaf(v.y, sc, sh);
        v.z = fmaf(v.z, sc, sh);
        v.w = fmaf(v.w, sc, sh);
        *p = v;
    } else if (base < N) {
        for (int t = base; t < N; ++t) y[(long)d * N + t] = fmaf(y[(long)d * N + t], sc, sh);
    }
}

// ---------------- launcher ----------------
extern "C" void kernel_launch(void* const* d_in, const int* in_sizes, int n_in,
                              void* d_out, int out_size, void* d_ws, size_t ws_size,
                              hipStream_t stream) {
    const float* data_in = (const float*)d_in[0];
    const int*   neigh   = (const int*)d_in[1];
    const float* weight  = (const float*)d_in[2];
    const float* gamma   = (const float*)d_in[3];
    const float* beta    = (const float*)d_in[4];
    float* out = (float*)d_out;

    const int N = in_sizes[1] / KK;

    float* xT = (float*)d_ws;                        // N*32 floats
    const int nblk  = (N + 63) / 64;                 // conv blocks (64 nodes each)
    const int nrows = nblk;
    float* partial = xT + (size_t)N * CIN;           // 64*nrows floats
    float* tot     = partial + (size_t)64 * nrows;   // 64 floats

    transpose_k<<<(N + 31) / 32, 256, 0, stream>>>(data_in, xT, N);
    conv_k<<<nblk, 256, 0, stream>>>(xT, neigh, weight, out, partial, N, nrows);
    stats1_k<<<64, 256, 0, stream>>>(partial, nrows, tot);
    dim3 ngrid(((N + 3) / 4 + 255) / 256, COUT);
    norm_k<<<ngrid, 256, 0, stream>>>(out, tot, gamma, beta, N);
}

// Round 6
// 136.919 us; speedup vs baseline: 4.4192x; 4.0014x over previous
//
#include <hip/hip_runtime.h>

#define KK 27

typedef short bf16x8 __attribute__((ext_vector_type(8)));   // 8 bf16 in 4 VGPRs
typedef float f32x4  __attribute__((ext_vector_type(4)));

__device__ inline unsigned short f2bf(float f) {            // RNE fp32 -> bf16
    unsigned u = __float_as_uint(f);
    unsigned r = u + 0x7fffu + ((u >> 16) & 1u);
    return (unsigned short)(r >> 16);
}

// ---- Kernel 1: x [32][N] fp32 -> xTb [N][32] bf16 (transpose + cast) ----
__global__ __launch_bounds__(256) void xprep_k(const float* __restrict__ in,
                                               unsigned short* __restrict__ xTb, int N) {
    __shared__ float tile[32][33];
    int n0 = blockIdx.x * 32;
    int tx = threadIdx.x & 31;
    int ty = threadIdx.x >> 5;  // 0..7
#pragma unroll
    for (int c = ty; c < 32; c += 8) {
        int n = n0 + tx;
        tile[c][tx] = (n < N) ? in[(long)c * N + n] : 0.f;
    }
    __syncthreads();
#pragma unroll
    for (int nn = ty; nn < 32; nn += 8) {
        int n = n0 + nn;
        if (n < N) xTb[(long)n * 32 + tx] = f2bf(tile[tx][nn]);
    }
}

// ---- Kernel 2: weight [27][cin=32][cout=32] fp32 -> wTb [27][cout=32][cin=32] bf16 ----
__global__ __launch_bounds__(256) void wprep_k(const float* __restrict__ w,
                                               unsigned short* __restrict__ wTb) {
    int k = blockIdx.x;
    for (int i = threadIdx.x; i < 1024; i += 256) {
        int cin = i >> 5, cout = i & 31;
        wTb[k * 1024 + cout * 32 + cin] = f2bf(w[k * 1024 + cin * 32 + cout]);
    }
}

// ---- Kernel 3: MFMA conv + BN partials ----
// One wave per 32 nodes. 4x mfma_f32_16x16x32_bf16 per tap (2 M-tiles x 2 N-tiles),
// 27 taps = K=864. A-frag: lane(m=L&15, k=quad*8+j) -> 16B from gathered bf16 row.
// B-frag: lane(n=L&15, k=quad*8+j) -> 16B from wTb[k][cout][cin]. fp32 accumulate.
// Epilogue: LDS transpose -> coalesced y stores; butterfly -> BN sum/sumsq partials.
__global__ __launch_bounds__(64, 4) void conv_k(const unsigned short* __restrict__ xTb,
                                                const int* __restrict__ neigh,
                                                const unsigned short* __restrict__ wTb,
                                                float* __restrict__ y,        // [32][N]
                                                float* __restrict__ partial,  // [64][nrows]
                                                int N, int nrows) {
    __shared__ float ct[32][33];

    const int L    = threadIdx.x;      // 0..63
    const int r16  = L & 15;
    const int quad = L >> 4;           // 0..3
    const int base = blockIdx.x * 32;
    const int n0 = base + r16;
    const int n1 = base + 16 + r16;
    const bool v0 = (n0 < N), v1 = (n1 < N);
    const long nb0 = (long)(v0 ? n0 : 0) * KK;
    const long nb1 = (long)(v1 ? n1 : 0) * KK;

    const bf16x8 zz = {0, 0, 0, 0, 0, 0, 0, 0};

    f32x4 acc00 = {0.f, 0.f, 0.f, 0.f};
    f32x4 acc01 = acc00, acc10 = acc00, acc11 = acc00;

    int ia = neigh[nb0];
    int ib = neigh[nb1];
    int ja = neigh[nb0 + 1];
    int jb = neigh[nb1 + 1];

    bf16x8 a0 = *(const bf16x8*)(xTb + (long)ia * 32 + quad * 8);
    bf16x8 a1 = *(const bf16x8*)(xTb + (long)ib * 32 + quad * 8);
    bf16x8 b0 = *(const bf16x8*)(wTb + r16 * 32 + quad * 8);
    bf16x8 b1 = *(const bf16x8*)(wTb + (16 + r16) * 32 + quad * 8);
    a0 = v0 ? a0 : zz;
    a1 = v1 ? a1 : zz;

#pragma unroll 1
    for (int k = 0; k < KK; ++k) {
        bf16x8 na0 = zz, na1 = zz, pb0 = zz, pb1 = zz;
        if (k < KK - 1) {
            na0 = *(const bf16x8*)(xTb + (long)ja * 32 + quad * 8);
            na1 = *(const bf16x8*)(xTb + (long)jb * 32 + quad * 8);
            const unsigned short* wn = wTb + (k + 1) * 1024;
            pb0 = *(const bf16x8*)(wn + r16 * 32 + quad * 8);
            pb1 = *(const bf16x8*)(wn + (16 + r16) * 32 + quad * 8);
            int kk = (k + 2 < KK) ? (k + 2) : (KK - 1);
            ja = neigh[nb0 + kk];
            jb = neigh[nb1 + kk];
        }

        acc00 = __builtin_amdgcn_mfma_f32_16x16x32_bf16(a0, b0, acc00, 0, 0, 0);
        acc01 = __builtin_amdgcn_mfma_f32_16x16x32_bf16(a0, b1, acc01, 0, 0, 0);
        acc10 = __builtin_amdgcn_mfma_f32_16x16x32_bf16(a1, b0, acc10, 0, 0, 0);
        acc11 = __builtin_amdgcn_mfma_f32_16x16x32_bf16(a1, b1, acc11, 0, 0, 0);

        if (k < KK - 1) {
            a0 = v0 ? na0 : zz;
            a1 = v1 ? na1 : zz;
            b0 = pb0;
            b1 = pb1;
        }
    }

    // BN partials straight from accumulators: sum over this wave's 32 nodes.
    // C/D layout: cout = L&15 (+16 for N-tile 1), node = quad*4 + reg (+16 for M-tile 1).
    float s0 = 0.f, q0 = 0.f, s1 = 0.f, q1 = 0.f;
#pragma unroll
    for (int r = 0; r < 4; ++r) {
        s0 += acc00[r] + acc10[r];
        q0 += acc00[r] * acc00[r] + acc10[r] * acc10[r];
        s1 += acc01[r] + acc11[r];
        q1 += acc01[r] * acc01[r] + acc11[r] * acc11[r];
    }
#pragma unroll
    for (int off = 16; off < 64; off <<= 1) {   // reduce across quads (m within tile)
        s0 += __shfl_xor(s0, off, 64);
        q0 += __shfl_xor(q0, off, 64);
        s1 += __shfl_xor(s1, off, 64);
        q1 += __shfl_xor(q1, off, 64);
    }
    if (L < 16) {
        const int b = blockIdx.x;
        partial[(long)L * nrows + b]        = s0;
        partial[(long)(L + 16) * nrows + b] = s1;
        partial[(long)(L + 32) * nrows + b] = q0;
        partial[(long)(L + 48) * nrows + b] = q1;
    }

    // LDS transpose -> coalesced y stores ([cout][node], node contiguous)
#pragma unroll
    for (int r = 0; r < 4; ++r) {
        ct[quad * 4 + r][r16]           = acc00[r];
        ct[quad * 4 + r][16 + r16]      = acc01[r];
        ct[16 + quad * 4 + r][r16]      = acc10[r];
        ct[16 + quad * 4 + r][16 + r16] = acc11[r];
    }
    __syncthreads();
    const int node = L & 31;
    const int half = L >> 5;
    const int gn = base + node;
#pragma unroll
    for (int i = 0; i < 16; ++i) {
        const int cout = i * 2 + half;
        if (gn < N) y[(long)cout * N + gn] = ct[node][cout];
    }
}

// ---- Kernel 4: column reduce partial[64][nrows] -> tot[64] ----
__global__ __launch_bounds__(256) void stats1_k(const float* __restrict__ partial,
                                                int nrows, float* __restrict__ tot) {
    __shared__ float red[256];
    const int col = blockIdx.x;  // 0..63
    const float* row = partial + (long)col * nrows;
    float s = 0.f;
    for (int r = threadIdx.x; r < nrows; r += 256) s += row[r];
    red[threadIdx.x] = s;
    __syncthreads();
    for (int w = 128; w >= 64; w >>= 1) {
        if (threadIdx.x < w) red[threadIdx.x] += red[threadIdx.x + w];
        __syncthreads();
    }
    if (threadIdx.x < 64) {
        float v = red[threadIdx.x];
#pragma unroll
        for (int off = 1; off < 64; off <<= 1) v += __shfl_xor(v, off, 64);
        if (threadIdx.x == 0) tot[col] = v;
    }
}

// ---- Kernel 5: normalize y in place (stats finalize fused) ----
__global__ __launch_bounds__(256) void norm_k(float* __restrict__ y,
                                              const float* __restrict__ tot,
                                              const float* __restrict__ gamma,
                                              const float* __restrict__ beta, int N) {
    const int d = blockIdx.y;
    const float mean = tot[d] / (float)N;
    const float var  = tot[d + 32] / (float)N - mean * mean;
    const float sc   = gamma[d] * rsqrtf(var + 1e-3f);
    const float sh   = beta[d] - mean * sc;

    int i = blockIdx.x * blockDim.x + threadIdx.x;
    int base = i * 4;
    if (base + 3 < N) {
        float4* p = (float4*)(y + (long)d * N + base);
        float4 v = *p;
        v.x = fmaf(v.x, sc, sh);
        v.y = fmaf(v.y, sc, sh);
        v.z = fmaf(v.z, sc, sh);
        v.w = fmaf(v.w, sc, sh);
        *p = v;
    } else if (base < N) {
        for (int t = base; t < N; ++t) y[(long)d * N + t] = fmaf(y[(long)d * N + t], sc, sh);
    }
}

// ---- launcher ----
extern "C" void kernel_launch(void* const* d_in, const int* in_sizes, int n_in,
                              void* d_out, int out_size, void* d_ws, size_t ws_size,
                              hipStream_t stream) {
    const float* data_in = (const float*)d_in[0];
    const int*   neigh   = (const int*)d_in[1];
    const float* weight  = (const float*)d_in[2];
    const float* gamma   = (const float*)d_in[3];
    const float* beta    = (const float*)d_in[4];
    float* out = (float*)d_out;

    const int N = in_sizes[1] / KK;
    const int nblk  = (N + 31) / 32;   // 32 nodes per (1-wave) conv block
    const int nrows = nblk;

    char* ws = (char*)d_ws;
    unsigned short* xTb = (unsigned short*)ws;                       // N*32 bf16
    unsigned short* wTb = (unsigned short*)(ws + (size_t)N * 64);    // 27*1024 bf16
    float* partial = (float*)(ws + (size_t)N * 64 + 55296);          // 64*nrows
    float* tot     = partial + (size_t)64 * nrows;                   // 64

    xprep_k<<<nblk, 256, 0, stream>>>(data_in, xTb, N);
    wprep_k<<<KK, 256, 0, stream>>>(weight, wTb);
    conv_k<<<nblk, 64, 0, stream>>>(xTb, neigh, wTb, out, partial, N, nrows);
    stats1_k<<<64, 256, 0, stream>>>(partial, nrows, tot);
    dim3 ngrid(((N + 3) / 4 + 255) / 256, 32);
    norm_k<<<ngrid, 256, 0, stream>>>(out, tot, gamma, beta, N);
}